// Round 2
// baseline (2356.990 us; speedup 1.0000x reference)
//
#include <hip/hip_runtime.h>

// MaxUnpooling2D: B=16, H=128, W=128, C=64, pool 2x2 -> OH=256, OW=256.
// out flat index (per batch) = (mask & ~63) | channel  (OW*C=16384, C=64 pow2).
//
// Two-phase binned scatter:
//   P1: route each (target,val) record into one of 8192 bins (bin = 32 KiB
//       contiguous output tile). Slot via atomicAdd on bin counters.
//   P2: one block per bin: zero 32 KiB LDS tile, replay records with LDS
//       atomics, stream tile to global. No output memset, no global atomics.
//   P3: overflow records (deterministically ~0) applied with global atomics.

constexpr int B_ = 16, H_ = 128, W_ = 128, C_ = 64;
constexpr int N  = B_ * H_ * W_ * C_;       // 16,777,216 updates
constexpr int N4 = N / 4;
constexpr int OUT_ELEMS = N * 4;            // 67,108,864 (256 MiB)

constexpr int BIN_SHIFT = 13;
constexpr int BIN_ELEMS = 1 << BIN_SHIFT;   // 8192 floats = 32 KiB tile
constexpr int BINS = OUT_ELEMS >> BIN_SHIFT; // 8192
constexpr int CAP  = 2432;                  // mean 2048/bin, +8.5 sigma slack
constexpr unsigned OVF_CAP = 65536;

// d_ws layout
constexpr size_t CNT_OFF  = 0;                             // uint[BINS]
constexpr size_t OVFC_OFF = (size_t)BINS * 4;              // 32768
constexpr size_t OVF_OFF  = OVFC_OFF + 16;                 // 32784 (16-aligned)
constexpr size_t REC_OFF  = OVF_OFF + (size_t)OVF_CAP * 8; // 557072 (16-aligned)
constexpr size_t WS_NEED  = REC_OFF + (size_t)BINS * CAP * 8; // ~152.5 MiB

__global__ __launch_bounds__(256) void p1_bin(
        const float4* __restrict__ upd4, const int4* __restrict__ msk4,
        unsigned* __restrict__ cnt, uint2* __restrict__ recs,
        unsigned* __restrict__ ovf_cnt, uint2* __restrict__ ovf) {
    int i4 = blockIdx.x * 256 + threadIdx.x;
    int i  = i4 << 2;
    float4 u = upd4[i4];
    int4   m = msk4[i4];
    unsigned base = ((unsigned)(i >> 20)) << 22;   // batch * OHOWC
    unsigned f    = i & 63;
    unsigned g[4] = { base | (unsigned)(m.x & ~63) | (f + 0),
                      base | (unsigned)(m.y & ~63) | (f + 1),
                      base | (unsigned)(m.z & ~63) | (f + 2),
                      base | (unsigned)(m.w & ~63) | (f + 3) };
    float    v[4] = { u.x, u.y, u.z, u.w };
#pragma unroll
    for (int k = 0; k < 4; ++k) {
        unsigned bin = g[k] >> BIN_SHIFT;
        unsigned idx = atomicAdd(&cnt[bin], 1u);
        if (idx < (unsigned)CAP) {
            recs[(size_t)bin * CAP + idx] =
                make_uint2(g[k] & (BIN_ELEMS - 1), __float_as_uint(v[k]));
        } else {
            unsigned oi = atomicAdd(ovf_cnt, 1u);
            if (oi < OVF_CAP) ovf[oi] = make_uint2(g[k], __float_as_uint(v[k]));
        }
    }
}

__global__ __launch_bounds__(256) void p2_replay(
        const uint2* __restrict__ recs, const unsigned* __restrict__ cnt,
        float* __restrict__ out) {
    __shared__ float tile[BIN_ELEMS];          // 32 KiB
    int bin = blockIdx.x;
    for (int i = threadIdx.x; i < BIN_ELEMS; i += 256) tile[i] = 0.0f;
    __syncthreads();
    int n = (int)cnt[bin];
    if (n > CAP) n = CAP;
    const uint2* r = recs + (size_t)bin * CAP;
    for (int i = threadIdx.x; i < n; i += 256) {
        uint2 rec = r[i];
        atomicAdd(&tile[rec.x], __uint_as_float(rec.y));
    }
    __syncthreads();
    float4*       o = (float4*)(out + ((size_t)bin << BIN_SHIFT));
    const float4* t = (const float4*)tile;
    for (int i = threadIdx.x; i < BIN_ELEMS / 4; i += 256) o[i] = t[i];
}

__global__ __launch_bounds__(256) void p3_overflow(
        const unsigned* __restrict__ ovf_cnt, const uint2* __restrict__ ovf,
        float* __restrict__ out) {
    unsigned n = *ovf_cnt;
    if (n > OVF_CAP) n = OVF_CAP;
    for (unsigned i = blockIdx.x * 256 + threadIdx.x; i < n; i += gridDim.x * 256)
        atomicAdd(out + ovf[i].x, __uint_as_float(ovf[i].y));
}

// ---- fallback path (ws too small): zero + direct atomic scatter ----
__global__ __launch_bounds__(256) void zero_out(float4* __restrict__ out4) {
    size_t i = (size_t)blockIdx.x * 256 + threadIdx.x;
    size_t stride = (size_t)gridDim.x * 256;
    for (size_t k = i; k < (size_t)OUT_ELEMS / 4; k += stride)
        out4[k] = make_float4(0.f, 0.f, 0.f, 0.f);
}

__global__ __launch_bounds__(256) void unpool_scatter(
        const float4* __restrict__ upd4, const int4* __restrict__ msk4,
        float* __restrict__ out) {
    int i4 = blockIdx.x * 256 + threadIdx.x;
    int i  = i4 << 2;
    float4 u = upd4[i4];
    int4   m = msk4[i4];
    int b = i >> 20;
    int f = i & 63;
    float* outb = out + ((size_t)b << 22);
    atomicAdd(outb + ((m.x & ~63) | (f + 0)), u.x);
    atomicAdd(outb + ((m.y & ~63) | (f + 1)), u.y);
    atomicAdd(outb + ((m.z & ~63) | (f + 2)), u.z);
    atomicAdd(outb + ((m.w & ~63) | (f + 3)), u.w);
}

extern "C" void kernel_launch(void* const* d_in, const int* in_sizes, int n_in,
                              void* d_out, int out_size, void* d_ws, size_t ws_size,
                              hipStream_t stream) {
    const float4* upd4 = (const float4*)d_in[0];
    const int4*   msk4 = (const int4*)d_in[1];
    float*        out  = (float*)d_out;

    if (ws_size >= WS_NEED) {
        char* ws = (char*)d_ws;
        unsigned* cnt     = (unsigned*)(ws + CNT_OFF);
        unsigned* ovf_cnt = (unsigned*)(ws + OVFC_OFF);
        uint2*    ovf     = (uint2*)(ws + OVF_OFF);
        uint2*    recs    = (uint2*)(ws + REC_OFF);

        hipMemsetAsync(ws, 0, OVF_OFF, stream);  // zero counters
        p1_bin<<<N4 / 256, 256, 0, stream>>>(upd4, msk4, cnt, recs, ovf_cnt, ovf);
        p2_replay<<<BINS, 256, 0, stream>>>(recs, cnt, out);
        p3_overflow<<<64, 256, 0, stream>>>(ovf_cnt, ovf, out);
    } else {
        zero_out<<<8192, 256, 0, stream>>>((float4*)out);
        unpool_scatter<<<N4 / 256, 256, 0, stream>>>(upd4, msk4, out);
    }
}

// Round 4
// 594.345 us; speedup vs baseline: 3.9657x; 3.9657x over previous
//
#include <hip/hip_runtime.h>

// MaxUnpooling2D B=16,H=128,W=128,C=64 -> out (16,256,256,64) f32 scatter-add.
// Full output index g = (batch<<22) | (mask & ~63) | (i & 63)  (26 bits).
//
// Processed in 2 halves (8 batches) so record buffers fit workspace.
//  P1: block-local counting sort of 4096-record chunks into 128 coarse bins
//      (per-half out region 2^18 elems = 1 MiB); coalesced run writes to
//      per-bin global segments (space reserved via one atomicAdd per bin/block).
//  P2: same counting-sort, splitting each coarse segment into 32 fine bins
//      (2^13 elems = 32 KiB out tile).
//  P3: per-fine-bin LDS-atomic replay + dense float4 tile write (covers the
//      whole output -> no memset of d_out needed).
//  P4: statistical-overflow spill records applied with global atomics.

constexpr int N      = 1 << 24;       // 16,777,216 updates
constexpr int HALF_N = N >> 1;        // 8,388,608 per half
constexpr int CSHIFT = 18;            // coarse region: 2^18 elems (per half: 128 bins)
constexpr int FSHIFT = 13;            // fine tile: 8192 elems = 32 KiB
constexpr int NC     = 128;           // coarse bins per half
constexpr int NF     = 32;            // fine bins per coarse
constexpr int NFINE  = NC * NF;       // 4096 fine bins per half
constexpr int CHUNK  = 4096;          // records per sort block (32 KiB staging)
constexpr int CAP1   = 66560;         // coarse seg capacity (mean 65536, +4 sigma)
constexpr int FCAP   = 2432;          // fine seg capacity  (mean 2048, +8.5 sigma)
constexpr int SUBS   = 17;            // ceil(CAP1/CHUNK) sub-blocks per coarse
constexpr unsigned OVF_CAP = 131072;

// workspace layout
constexpr size_t GC1_OFF  = 0;                              // 128 u32
constexpr size_t GC2_OFF  = 512;                            // 4096 u32
constexpr size_t OVFC_OFF = 512 + 16384;                    // 16896
constexpr size_t HDR_ZERO = OVFC_OFF;                       // re-zeroed per half
constexpr size_t OVF_OFF  = 16912;                          // 16-aligned
constexpr size_t REC1_OFF = OVF_OFF + (size_t)OVF_CAP * 8;          // 1,065,488
constexpr size_t REC2_OFF = REC1_OFF + (size_t)NC * CAP1 * 8;       // 69,222,928
constexpr size_t WS_NEED  = REC2_OFF + (size_t)NFINE * FCAP * 8;    // ~142 MiB

__device__ __forceinline__ void spill(unsigned* ovf_cnt, uint2* ovf,
                                      unsigned g, unsigned v) {
    unsigned oi = atomicAdd(ovf_cnt, 1u);
    if (oi < OVF_CAP) ovf[oi] = make_uint2(g, v);
}

__global__ __launch_bounds__(256) void p1(const float4* __restrict__ upd4,
                                          const int4* __restrict__ msk4,
                                          unsigned* __restrict__ gcnt1,
                                          uint2* __restrict__ recs1,
                                          unsigned* __restrict__ ovf_cnt,
                                          uint2* __restrict__ ovf, int half) {
    __shared__ uint2 sorted[CHUNK];                       // 32 KiB
    __shared__ unsigned hist[NC], scan[NC], startx[NC], offs[NC], gbase[NC];
    const int tid = threadIdx.x;
    const int rec_base = half * HALF_N + blockIdx.x * CHUNK;
    if (tid < NC) hist[tid] = 0;
    __syncthreads();
    // pass A: histogram (mask only)
#pragma unroll
    for (int k = 0; k < CHUNK / 4 / 256; ++k) {
        int q = (rec_base >> 2) + k * 256 + tid;          // float4 index
        int4 m = msk4[q];
        int i = q << 2;
        unsigned gb = ((unsigned)(i >> 20) << 22) | (unsigned)(i & 63);
        atomicAdd(&hist[(((gb + 0) | (unsigned)(m.x & ~63)) >> CSHIFT) & (NC - 1)], 1u);
        atomicAdd(&hist[(((gb + 1) | (unsigned)(m.y & ~63)) >> CSHIFT) & (NC - 1)], 1u);
        atomicAdd(&hist[(((gb + 2) | (unsigned)(m.z & ~63)) >> CSHIFT) & (NC - 1)], 1u);
        atomicAdd(&hist[(((gb + 3) | (unsigned)(m.w & ~63)) >> CSHIFT) & (NC - 1)], 1u);
    }
    __syncthreads();
    // exclusive prefix scan over NC bins (Hillis-Steele)
    if (tid < NC) scan[tid] = hist[tid];
    __syncthreads();
    for (int d = 1; d < NC; d <<= 1) {
        unsigned v = 0;
        if (tid < NC && tid >= d) v = scan[tid - d];
        __syncthreads();
        if (tid < NC) scan[tid] += v;
        __syncthreads();
    }
    if (tid < NC) {
        unsigned s = scan[tid] - hist[tid];
        startx[tid] = s;
        offs[tid]   = s;
        gbase[tid]  = atomicAdd(&gcnt1[tid], hist[tid]);
    }
    __syncthreads();
    // pass B: scatter into sorted LDS buffer
#pragma unroll
    for (int k = 0; k < CHUNK / 4 / 256; ++k) {
        int q = (rec_base >> 2) + k * 256 + tid;
        float4 u = upd4[q];
        int4   m = msk4[q];
        int i = q << 2;
        unsigned gb = ((unsigned)(i >> 20) << 22) | (unsigned)(i & 63);
        unsigned g[4] = { (gb + 0) | (unsigned)(m.x & ~63),
                          (gb + 1) | (unsigned)(m.y & ~63),
                          (gb + 2) | (unsigned)(m.z & ~63),
                          (gb + 3) | (unsigned)(m.w & ~63) };
        float v[4] = { u.x, u.y, u.z, u.w };
#pragma unroll
        for (int e = 0; e < 4; ++e) {
            unsigned c = (g[e] >> CSHIFT) & (NC - 1);
            unsigned pos = atomicAdd(&offs[c], 1u);
            sorted[pos] = make_uint2(g[e], __float_as_uint(v[e]));
        }
    }
    __syncthreads();
    // pass C: coalesced run copy-out
    for (int j = tid; j < CHUNK; j += 256) {
        uint2 r = sorted[j];
        unsigned c = (r.x >> CSHIFT) & (NC - 1);
        unsigned s = gbase[c] + (unsigned)j - startx[c];
        if (s < (unsigned)CAP1) recs1[(size_t)c * CAP1 + s] = r;
        else spill(ovf_cnt, ovf, r.x, r.y);
    }
}

__global__ __launch_bounds__(256) void p2(const uint2* __restrict__ recs1,
                                          const unsigned* __restrict__ gcnt1,
                                          unsigned* __restrict__ gcnt2,
                                          uint2* __restrict__ recs2,
                                          unsigned* __restrict__ ovf_cnt,
                                          uint2* __restrict__ ovf) {
    __shared__ uint2 sorted[CHUNK];                       // 32 KiB
    __shared__ unsigned hist[NF], scan[NF], startx[NF], offs[NF], gbase[NF];
    const int tid = threadIdx.x;
    const int c = blockIdx.x / SUBS, sub = blockIdx.x % SUBS;
    int n1 = (int)min(gcnt1[c], (unsigned)CAP1);
    int start = sub * CHUNK;
    int end = min(start + CHUNK, n1);
    int cnt = end - start;                                // may be <= 0
    if (tid < NF) hist[tid] = 0;
    __syncthreads();
    const uint2* seg1 = recs1 + (size_t)c * CAP1 + start;
    for (int j = tid; j < cnt; j += 256)
        atomicAdd(&hist[(seg1[j].x >> FSHIFT) & (NF - 1)], 1u);
    __syncthreads();
    if (tid < NF) scan[tid] = hist[tid];
    __syncthreads();
    for (int d = 1; d < NF; d <<= 1) {
        unsigned v = 0;
        if (tid < NF && tid >= d) v = scan[tid - d];
        __syncthreads();
        if (tid < NF) scan[tid] += v;
        __syncthreads();
    }
    if (tid < NF) {
        unsigned s = scan[tid] - hist[tid];
        startx[tid] = s;
        offs[tid]   = s;
        gbase[tid]  = atomicAdd(&gcnt2[(unsigned)c * NF + tid], hist[tid]);
    }
    __syncthreads();
    for (int j = tid; j < cnt; j += 256) {
        uint2 r = seg1[j];
        unsigned f = (r.x >> FSHIFT) & (NF - 1);
        unsigned pos = atomicAdd(&offs[f], 1u);
        sorted[pos] = r;
    }
    __syncthreads();
    for (int j = tid; j < cnt; j += 256) {
        uint2 r = sorted[j];
        unsigned f = (r.x >> FSHIFT) & (NF - 1);
        unsigned s = gbase[f] + (unsigned)j - startx[f];
        if (s < (unsigned)FCAP)
            recs2[(size_t)((unsigned)c * NF + f) * FCAP + s] = r;
        else spill(ovf_cnt, ovf, r.x, r.y);
    }
}

__global__ __launch_bounds__(256) void p3(const uint2* __restrict__ recs2,
                                          const unsigned* __restrict__ gcnt2,
                                          float* __restrict__ out, int half) {
    __shared__ float tile[1 << FSHIFT];                   // 32 KiB
    const int tid = threadIdx.x;
    const unsigned fi = blockIdx.x;
    for (int i = tid; i < (1 << FSHIFT); i += 256) tile[i] = 0.0f;
    __syncthreads();
    int n = (int)min(gcnt2[fi], (unsigned)FCAP);
    const uint2* seg = recs2 + (size_t)fi * FCAP;
    for (int i = tid; i < n; i += 256) {
        uint2 r = seg[i];
        atomicAdd(&tile[r.x & ((1u << FSHIFT) - 1)], __uint_as_float(r.y));
    }
    __syncthreads();
    float4* o = (float4*)(out + ((size_t)half << 25) + ((size_t)fi << FSHIFT));
    const float4* t4 = (const float4*)tile;
    for (int i = tid; i < (1 << FSHIFT) / 4; i += 256) o[i] = t4[i];
}

__global__ __launch_bounds__(256) void p4(const unsigned* __restrict__ ovf_cnt,
                                          const uint2* __restrict__ ovf,
                                          float* __restrict__ out) {
    unsigned n = min(*ovf_cnt, OVF_CAP);
    for (unsigned i = blockIdx.x * 256 + threadIdx.x; i < n; i += gridDim.x * 256)
        atomicAdd(out + ovf[i].x, __uint_as_float(ovf[i].y));
}

// ---- fallback (ws too small): round-1 path, known-correct ----
__global__ __launch_bounds__(256) void zero_out(float4* __restrict__ out4) {
    size_t i = (size_t)blockIdx.x * 256 + threadIdx.x;
    size_t stride = (size_t)gridDim.x * 256;
    for (size_t k = i; k < (size_t)N; k += stride)
        out4[k] = make_float4(0.f, 0.f, 0.f, 0.f);
}
__global__ __launch_bounds__(256) void unpool_scatter(
        const float4* __restrict__ upd4, const int4* __restrict__ msk4,
        float* __restrict__ out) {
    int i4 = blockIdx.x * 256 + threadIdx.x;
    int i  = i4 << 2;
    float4 u = upd4[i4];
    int4   m = msk4[i4];
    float* outb = out + ((size_t)(i >> 20) << 22);
    int f = i & 63;
    atomicAdd(outb + ((m.x & ~63) | (f + 0)), u.x);
    atomicAdd(outb + ((m.y & ~63) | (f + 1)), u.y);
    atomicAdd(outb + ((m.z & ~63) | (f + 2)), u.z);
    atomicAdd(outb + ((m.w & ~63) | (f + 3)), u.w);
}

extern "C" void kernel_launch(void* const* d_in, const int* in_sizes, int n_in,
                              void* d_out, int out_size, void* d_ws, size_t ws_size,
                              hipStream_t stream) {
    const float* updates = (const float*)d_in[0];
    const int*   mask    = (const int*)d_in[1];
    float*       out     = (float*)d_out;

    if (ws_size >= WS_NEED) {
        char* ws = (char*)d_ws;
        unsigned* gcnt1   = (unsigned*)(ws + GC1_OFF);
        unsigned* gcnt2   = (unsigned*)(ws + GC2_OFF);
        unsigned* ovf_cnt = (unsigned*)(ws + OVFC_OFF);
        uint2*    ovf     = (uint2*)(ws + OVF_OFF);
        uint2*    recs1   = (uint2*)(ws + REC1_OFF);
        uint2*    recs2   = (uint2*)(ws + REC2_OFF);

        hipMemsetAsync(ws, 0, OVF_OFF, stream);                 // all counters
        for (int h = 0; h < 2; ++h) {
            if (h) hipMemsetAsync(ws, 0, HDR_ZERO, stream);     // gcnt1+gcnt2
            p1<<<HALF_N / CHUNK, 256, 0, stream>>>(
                (const float4*)updates, (const int4*)mask,
                gcnt1, recs1, ovf_cnt, ovf, h);
            p2<<<NC * SUBS, 256, 0, stream>>>(recs1, gcnt1, gcnt2, recs2,
                                              ovf_cnt, ovf);
            p3<<<NFINE, 256, 0, stream>>>(recs2, gcnt2, out, h);
        }
        p4<<<64, 256, 0, stream>>>(ovf_cnt, ovf, out);
    } else {
        zero_out<<<8192, 256, 0, stream>>>((float4*)out);
        unpool_scatter<<<N / 4 / 256, 256, 0, stream>>>(
            (const float4*)updates, (const int4*)mask, out);
    }
}

// Round 5
// 482.432 us; speedup vs baseline: 4.8856x; 1.2320x over previous
//
#include <hip/hip_runtime.h>

// MaxUnpooling2D B=16,H=128,W=128,C=64 -> out (16,256,256,64) f32 scatter-add.
// Full output index g = (batch<<22) | (mask & ~63) | (i & 63)  (26 bits).
//
// Single-level binned scatter (ws >= ~161 MB; harness provides ~1 GiB):
//  P1: block-local counting sort of 8192-record chunks into 512 fine bins
//      (each chunk sits in ONE batch; fine bin = 8192-elem = 32 KiB out tile).
//      Avg run/bin = 16 records = 128 B -> coalesced segment writes. One
//      global atomicAdd per (block,bin) reserves segment space.
//  P3: one block per fine bin: LDS-atomic replay of its segment + dense
//      float4 tile write (covers whole output -> no d_out memset).
//  P4: statistical-overflow spills applied with global atomics.

constexpr int N      = 1 << 24;        // 16,777,216 updates
constexpr int FSHIFT = 13;             // fine tile: 8192 elems = 32 KiB
constexpr int NB     = 512;            // fine bins per batch (per block)
constexpr int NFINE  = 8192;           // fine bins total (16 batches * 512)
constexpr int CHUNK  = 8192;           // records per sort block (64 KiB staging)
constexpr int RPT    = 16;             // records per thread (512 threads)
constexpr int FCAP   = 2432;           // segment capacity (mean 2048 + 8.5 sigma)
constexpr unsigned OVF_CAP = 131072;

// workspace layout
constexpr size_t GC_OFF   = 0;                               // 8192 u32 = 32 KiB
constexpr size_t OVFC_OFF = (size_t)NFINE * 4;               // 32768
constexpr size_t OVF_OFF  = OVFC_OFF + 16;                   // 32784
constexpr size_t REC_OFF  = OVF_OFF + (size_t)OVF_CAP * 8;   // 1,081,360
constexpr size_t WS_NEED  = REC_OFF + (size_t)NFINE * FCAP * 8;  // ~160.5 MB

__device__ __forceinline__ void spill(unsigned* ovf_cnt, uint2* ovf,
                                      unsigned g, unsigned v) {
    unsigned oi = atomicAdd(ovf_cnt, 1u);
    if (oi < OVF_CAP) ovf[oi] = make_uint2(g, v);
}

__global__ __launch_bounds__(512) void p1(const float4* __restrict__ upd4,
                                          const int4* __restrict__ msk4,
                                          unsigned* __restrict__ gcnt,
                                          uint2* __restrict__ recs,
                                          unsigned* __restrict__ ovf_cnt,
                                          uint2* __restrict__ ovf) {
    __shared__ uint2 sorted[CHUNK];                       // 64 KiB
    __shared__ unsigned hist[NB], scanb[NB], startx[NB], offs[NB], gbase[NB];
    const int tid = threadIdx.x;
    const int q0 = blockIdx.x * (CHUNK / 4);              // base float4 index
    unsigned g[RPT];                                      // decoded out indices

    hist[tid] = 0;
    __syncthreads();
    // pass A: decode + histogram (mask only; indices kept in registers)
#pragma unroll
    for (int k = 0; k < 4; ++k) {
        int q = q0 + k * 512 + tid;
        int4 m = msk4[q];
        int i = q << 2;
        unsigned gb = ((unsigned)(i >> 20) << 22) | (unsigned)(i & 63);
        g[4 * k + 0] = (gb + 0) | (unsigned)(m.x & ~63);
        g[4 * k + 1] = (gb + 1) | (unsigned)(m.y & ~63);
        g[4 * k + 2] = (gb + 2) | (unsigned)(m.z & ~63);
        g[4 * k + 3] = (gb + 3) | (unsigned)(m.w & ~63);
#pragma unroll
        for (int e = 0; e < 4; ++e)
            atomicAdd(&hist[(g[4 * k + e] >> FSHIFT) & (NB - 1)], 1u);
    }
    __syncthreads();
    // exclusive prefix scan over NB=512 bins (Hillis-Steele, 512 threads)
    scanb[tid] = hist[tid];
    __syncthreads();
    for (int d = 1; d < NB; d <<= 1) {
        unsigned v = (tid >= d) ? scanb[tid - d] : 0u;
        __syncthreads();
        scanb[tid] += v;
        __syncthreads();
    }
    {
        unsigned s = scanb[tid] - hist[tid];
        startx[tid] = s;
        offs[tid]   = s;
        // global fine-bin id = (batch<<9) | local bin; batch = q0>>18
        gbase[tid]  = atomicAdd(&gcnt[(unsigned)(q0 >> 18) * NB + tid], hist[tid]);
    }
    __syncthreads();
    // pass B: scatter (value load + LDS placement)
#pragma unroll
    for (int k = 0; k < 4; ++k) {
        int q = q0 + k * 512 + tid;
        float4 u = upd4[q];
        float v[4] = { u.x, u.y, u.z, u.w };
#pragma unroll
        for (int e = 0; e < 4; ++e) {
            unsigned gg = g[4 * k + e];
            unsigned c = (gg >> FSHIFT) & (NB - 1);
            unsigned pos = atomicAdd(&offs[c], 1u);
            sorted[pos] = make_uint2(gg, __float_as_uint(v[e]));
        }
    }
    __syncthreads();
    // pass C: coalesced run copy-out to per-bin global segments
    for (int j = tid; j < CHUNK; j += 512) {
        uint2 r = sorted[j];
        unsigned c = (r.x >> FSHIFT) & (NB - 1);
        unsigned s = gbase[c] + (unsigned)j - startx[c];
        if (s < (unsigned)FCAP) recs[(size_t)(r.x >> FSHIFT) * FCAP + s] = r;
        else spill(ovf_cnt, ovf, r.x, r.y);
    }
}

__global__ __launch_bounds__(256) void p3(const uint2* __restrict__ recs,
                                          const unsigned* __restrict__ gcnt,
                                          float* __restrict__ out) {
    __shared__ float tile[1 << FSHIFT];                   // 32 KiB
    const int tid = threadIdx.x;
    const unsigned fi = blockIdx.x;
    for (int i = tid; i < (1 << FSHIFT); i += 256) tile[i] = 0.0f;
    __syncthreads();
    int n = (int)min(gcnt[fi], (unsigned)FCAP);
    const uint2* seg = recs + (size_t)fi * FCAP;
    for (int i = tid; i < n; i += 256) {
        uint2 r = seg[i];
        atomicAdd(&tile[r.x & ((1u << FSHIFT) - 1)], __uint_as_float(r.y));
    }
    __syncthreads();
    float4* o = (float4*)(out + ((size_t)fi << FSHIFT));
    const float4* t4 = (const float4*)tile;
    for (int i = tid; i < (1 << FSHIFT) / 4; i += 256) o[i] = t4[i];
}

__global__ __launch_bounds__(256) void p4(const unsigned* __restrict__ ovf_cnt,
                                          const uint2* __restrict__ ovf,
                                          float* __restrict__ out) {
    unsigned n = min(*ovf_cnt, OVF_CAP);
    for (unsigned i = blockIdx.x * 256 + threadIdx.x; i < n; i += gridDim.x * 256)
        atomicAdd(out + ovf[i].x, __uint_as_float(ovf[i].y));
}

// ---- fallback (ws too small): round-1 path, known-correct ----
__global__ __launch_bounds__(256) void zero_out(float4* __restrict__ out4) {
    size_t i = (size_t)blockIdx.x * 256 + threadIdx.x;
    size_t stride = (size_t)gridDim.x * 256;
    for (size_t k = i; k < (size_t)N; k += stride)
        out4[k] = make_float4(0.f, 0.f, 0.f, 0.f);
}
__global__ __launch_bounds__(256) void unpool_scatter(
        const float4* __restrict__ upd4, const int4* __restrict__ msk4,
        float* __restrict__ out) {
    int i4 = blockIdx.x * 256 + threadIdx.x;
    int i  = i4 << 2;
    float4 u = upd4[i4];
    int4   m = msk4[i4];
    float* outb = out + ((size_t)(i >> 20) << 22);
    int f = i & 63;
    atomicAdd(outb + ((m.x & ~63) | (f + 0)), u.x);
    atomicAdd(outb + ((m.y & ~63) | (f + 1)), u.y);
    atomicAdd(outb + ((m.z & ~63) | (f + 2)), u.z);
    atomicAdd(outb + ((m.w & ~63) | (f + 3)), u.w);
}

extern "C" void kernel_launch(void* const* d_in, const int* in_sizes, int n_in,
                              void* d_out, int out_size, void* d_ws, size_t ws_size,
                              hipStream_t stream) {
    const float* updates = (const float*)d_in[0];
    const int*   mask    = (const int*)d_in[1];
    float*       out     = (float*)d_out;

    if (ws_size >= WS_NEED) {
        char* ws = (char*)d_ws;
        unsigned* gcnt    = (unsigned*)(ws + GC_OFF);
        unsigned* ovf_cnt = (unsigned*)(ws + OVFC_OFF);
        uint2*    ovf     = (uint2*)(ws + OVF_OFF);
        uint2*    recs    = (uint2*)(ws + REC_OFF);

        hipMemsetAsync(ws, 0, OVF_OFF, stream);           // gcnt + ovf_cnt
        p1<<<N / CHUNK, 512, 0, stream>>>(
            (const float4*)updates, (const int4*)mask, gcnt, recs, ovf_cnt, ovf);
        p3<<<NFINE, 256, 0, stream>>>(recs, gcnt, out);
        p4<<<64, 256, 0, stream>>>(ovf_cnt, ovf, out);
    } else {
        zero_out<<<8192, 256, 0, stream>>>((float4*)out);
        unpool_scatter<<<N / 4 / 256, 256, 0, stream>>>(
            (const float4*)updates, (const int4*)mask, out);
    }
}